// Round 1
// baseline (270.045 us; speedup 1.0000x reference)
//
#include <hip/hip_runtime.h>
#include <math.h>

// Problem constants
#define N_ 16
#define T_ 8192
#define C_ 128
#define K_ 64

// main kernel tiling
#define BPN 32   // blocks per n
#define TPB 256  // t per block
#define TILE 32  // t per LDS tile

// ws layout in floats
#define WS_VLAD 0              // N*K*C = 131072
#define WS_ASUM 131072         // N*K  = 1024
#define WS_GSUM 132096         // N    = 16 (+ pad)
#define WS_ZEND 132608         // zeroed region end
#define WS_RNORM 132608        // N*T = 131072
#define WS_TOTAL (WS_RNORM + N_ * T_)

__global__ void zero_ws(float* ws) {
    int i = blockIdx.x * 256 + threadIdx.x;
    if (i < WS_ZEND) ws[i] = 0.0f;
}

// 1 / max(||x[n,t,:]||, 1e-12), one wave per (n,t) row
__global__ void rnorm_k(const float* __restrict__ x, float* __restrict__ ws) {
    int row = blockIdx.x * 4 + (threadIdx.x >> 6);
    int lane = threadIdx.x & 63;
    const float* xr = x + (size_t)row * C_;
    float a = xr[lane], b = xr[lane + 64];
    float ss = a * a + b * b;
#pragma unroll
    for (int m = 1; m < 64; m <<= 1) ss += __shfl_xor(ss, m, 64);
    if (lane == 0) ws[WS_RNORM + row] = 1.0f / fmaxf(sqrtf(ss), 1e-12f);
}

// Fused: normalize -> dwconv3 -> bn1+relu -> 1x1 conv -> bn2+relu -> mask
// -> softmax over K -> accumulate vlad (a x^T) and asum, atomically.
__global__ __launch_bounds__(256) void main_k(
    const float* __restrict__ x,
    const float* __restrict__ conv1_w,
    const float* __restrict__ bn1_g, const float* __restrict__ bn1_b,
    const float* __restrict__ bn1_m, const float* __restrict__ bn1_v,
    const float* __restrict__ conv2_w, const float* __restrict__ conv2_b,
    const float* __restrict__ bn2_g, const float* __restrict__ bn2_b,
    const float* __restrict__ bn2_m, const float* __restrict__ bn2_v,
    const int* __restrict__ length,
    float* __restrict__ ws) {

    __shared__ __align__(16) float w2s[K_][132];     // padded: conflict-free b128
    __shared__ __align__(16) float xtile[TILE][132];
    __shared__ __align__(16) float atile[TILE][68];
    __shared__ __align__(16) float hs[4][128];       // per-wave h scratch
    __shared__ float scale1[C_], shift1[C_], w1a[C_], w1b[C_], w1c[C_];
    __shared__ float scale2[K_], shift2[K_];

    const int tid = threadIdx.x;
    const int n = blockIdx.x / BPN;
    const int tb = (blockIdx.x % BPN) * TPB;

    for (int i = tid; i < C_; i += 256) {
        float s = bn1_g[i] * rsqrtf(bn1_v[i] + 1e-5f);
        scale1[i] = s;
        shift1[i] = bn1_b[i] - bn1_m[i] * s;
        w1a[i] = conv1_w[i * 9 + 1];  // kh=0, kw=1
        w1b[i] = conv1_w[i * 9 + 4];  // kh=1, kw=1
        w1c[i] = conv1_w[i * 9 + 7];  // kh=2, kw=1
    }
    for (int i = tid; i < K_; i += 256) {
        float s = bn2_g[i] * rsqrtf(bn2_v[i] + 1e-5f);
        scale2[i] = s;
        shift2[i] = s * conv2_b[i] + bn2_b[i] - bn2_m[i] * s;
    }
    for (int i = tid; i < K_ * C_; i += 256) w2s[i >> 7][i & 127] = conv2_w[i];

    const int L = length[n];
    const int w = tid >> 6, lane = tid & 63;
    const float* rn = ws + WS_RNORM + (size_t)n * T_;
    const float* xb = x + (size_t)n * T_ * C_;

    const int k0 = (tid >> 4) * 4;   // 0..60
    const int c0 = (tid & 15) * 8;   // 0..120

    float acc[4][8];
#pragma unroll
    for (int i = 0; i < 4; ++i)
#pragma unroll
        for (int j = 0; j < 8; ++j) acc[i][j] = 0.0f;
    float asum = 0.0f;

    __syncthreads();

    for (int tile = 0; tile < TPB / TILE; ++tile) {
        const int tbase = tb + tile * TILE;
        // ---- phase A: wave per t ----
        for (int j = 0; j < 8; ++j) {
            const int tt = w * 8 + j;
            const int t = tbase + tt;
            const float* xr = xb + (size_t)t * C_;
            float x0 = xr[lane], x1 = xr[lane + 64];
            float r0 = rn[t];
            float xn0 = x0 * r0, xn1 = x1 * r0;
            xtile[tt][lane] = xn0;
            xtile[tt][lane + 64] = xn1;
            if (t < L) {
                float hm0 = 0.f, hm1 = 0.f, hp0 = 0.f, hp1 = 0.f;
                if (t > 0) {
                    float rm = rn[t - 1];
                    hm0 = xr[lane - C_] * rm;
                    hm1 = xr[lane + 64 - C_] * rm;
                }
                if (t < T_ - 1) {
                    float rp = rn[t + 1];
                    hp0 = xr[lane + C_] * rp;
                    hp1 = xr[lane + 64 + C_] * rp;
                }
                float h0 = hm0 * w1a[lane] + xn0 * w1b[lane] + hp0 * w1c[lane];
                float h1 = hm1 * w1a[lane + 64] + xn1 * w1b[lane + 64] + hp1 * w1c[lane + 64];
                h0 = fmaxf(0.f, h0 * scale1[lane] + shift1[lane]);
                h1 = fmaxf(0.f, h1 * scale1[lane + 64] + shift1[lane + 64]);
                hs[w][lane] = h0;
                hs[w][lane + 64] = h1;
                // ensure the wave's LDS writes complete before cross-lane reads
                asm volatile("s_waitcnt lgkmcnt(0)" ::: "memory");
                float4 sv = {0.f, 0.f, 0.f, 0.f};
#pragma unroll
                for (int q = 0; q < 32; ++q) {
                    float4 hv = *(const float4*)&hs[w][q * 4];
                    float4 wv = *(const float4*)&w2s[lane][q * 4];
                    sv.x += hv.x * wv.x;
                    sv.y += hv.y * wv.y;
                    sv.z += hv.z * wv.z;
                    sv.w += hv.w * wv.w;
                }
                float s = (sv.x + sv.y) + (sv.z + sv.w);
                float logit = fmaxf(0.f, s * scale2[lane] + shift2[lane]);
                float m = logit;
#pragma unroll
                for (int mm = 1; mm < 64; mm <<= 1) m = fmaxf(m, __shfl_xor(m, mm, 64));
                float e = __expf(logit - m);
                float se = e;
#pragma unroll
                for (int mm = 1; mm < 64; mm <<= 1) se += __shfl_xor(se, mm, 64);
                atile[tt][lane] = e / se;
            } else {
                atile[tt][lane] = 1.0f / 64.0f;  // softmax of all-equal(-1e18) row
            }
        }
        __syncthreads();
        // ---- phase B: register-tiled rank-1 accumulation ----
#pragma unroll 4
        for (int tt = 0; tt < TILE; ++tt) {
            float4 av = *(const float4*)&atile[tt][k0];
            float4 xv0 = *(const float4*)&xtile[tt][c0];
            float4 xv1 = *(const float4*)&xtile[tt][c0 + 4];
            float aa[4] = {av.x, av.y, av.z, av.w};
            float xx[8] = {xv0.x, xv0.y, xv0.z, xv0.w, xv1.x, xv1.y, xv1.z, xv1.w};
#pragma unroll
            for (int i = 0; i < 4; ++i)
#pragma unroll
                for (int jj = 0; jj < 8; ++jj) acc[i][jj] += aa[i] * xx[jj];
        }
        if (tid < 64) {
#pragma unroll 8
            for (int tt = 0; tt < TILE; ++tt) asum += atile[tt][tid];
        }
        __syncthreads();
    }

    float* vlad = ws + WS_VLAD + (size_t)n * (K_ * C_);
#pragma unroll
    for (int i = 0; i < 4; ++i)
#pragma unroll
        for (int jj = 0; jj < 8; ++jj)
            atomicAdd(&vlad[(k0 + i) * C_ + c0 + jj], acc[i][jj]);
    if (tid < 64) atomicAdd(&ws[WS_ASUM + n * K_ + tid], asum);
}

// per (n,k) row: subtract asum*centroid, intra-L2-normalize, accumulate gsum
__global__ void finalize_k(const float* __restrict__ cent, float* __restrict__ ws,
                           float* __restrict__ out) {
    int row = blockIdx.x * 4 + (threadIdx.x >> 6);  // n*64 + k
    int lane = threadIdx.x & 63;
    int n = row >> 6, k = row & 63;
    const float* v = ws + WS_VLAD + (size_t)row * C_;
    float as = ws[WS_ASUM + row];
    float y0 = v[lane] - as * cent[k * C_ + lane];
    float y1 = v[lane + 64] - as * cent[k * C_ + lane + 64];
    float ss = y0 * y0 + y1 * y1;
#pragma unroll
    for (int m = 1; m < 64; m <<= 1) ss += __shfl_xor(ss, m, 64);
    float rs = 1.0f / fmaxf(sqrtf(ss), 1e-12f);
    out[(size_t)row * C_ + lane] = y0 * rs;
    out[(size_t)row * C_ + lane + 64] = y1 * rs;
    if (lane == 0) atomicAdd(&ws[WS_GSUM + n], ss * rs * rs);
}

__global__ void gscale_k(float* __restrict__ out, const float* __restrict__ ws) {
    int idx = blockIdx.x * 256 + threadIdx.x;  // < N*K*C
    int n = idx >> 13;
    float g = ws[WS_GSUM + n];
    out[idx] *= 1.0f / fmaxf(sqrtf(g), 1e-12f);
}

extern "C" void kernel_launch(void* const* d_in, const int* in_sizes, int n_in,
                              void* d_out, int out_size, void* d_ws, size_t ws_size,
                              hipStream_t stream) {
    const float* x       = (const float*)d_in[0];
    const float* conv1_w = (const float*)d_in[1];
    const float* bn1_g   = (const float*)d_in[2];
    const float* bn1_b   = (const float*)d_in[3];
    const float* bn1_m   = (const float*)d_in[4];
    const float* bn1_v   = (const float*)d_in[5];
    const float* conv2_w = (const float*)d_in[6];
    const float* conv2_b = (const float*)d_in[7];
    const float* bn2_g   = (const float*)d_in[8];
    const float* bn2_b   = (const float*)d_in[9];
    const float* bn2_m   = (const float*)d_in[10];
    const float* bn2_v   = (const float*)d_in[11];
    const float* cent    = (const float*)d_in[12];
    const int*   length  = (const int*)d_in[13];
    float* out = (float*)d_out;
    float* ws  = (float*)d_ws;

    zero_ws<<<(WS_ZEND + 255) / 256, 256, 0, stream>>>(ws);
    rnorm_k<<<N_ * T_ / 4, 256, 0, stream>>>(x, ws);
    main_k<<<N_ * BPN, 256, 0, stream>>>(x, conv1_w, bn1_g, bn1_b, bn1_m, bn1_v,
                                         conv2_w, conv2_b, bn2_g, bn2_b, bn2_m, bn2_v,
                                         length, ws);
    finalize_k<<<(N_ * K_) / 4, 256, 0, stream>>>(cent, ws, out);
    gscale_k<<<(N_ * K_ * C_) / 256, 256, 0, stream>>>(out, ws);
}